// Round 1
// baseline (17306.131 us; speedup 1.0000x reference)
//
#include <hip/hip_runtime.h>
#include <hip/hip_bf16.h>
#include <stdint.h>

#define B_ 8
#define S_ 512
#define H_ 1024
#define V_ 32000
#define D_ 768
#define G3H (3*H_)
#define GRU_BLOCKS 128

typedef __bf16 bf16x8_t __attribute__((ext_vector_type(8)));
typedef float f32x4_t __attribute__((ext_vector_type(4)));

__device__ __forceinline__ unsigned short f2bf(float f) {
  unsigned int u = __float_as_uint(f);
  u += 0x7fffu + ((u >> 16) & 1u);      // RNE
  return (unsigned short)(u >> 16);
}
__device__ __forceinline__ float fast_sigmoid(float x) {
  float e = __builtin_amdgcn_exp2f(x * -1.44269504088896340736f);
  return __builtin_amdgcn_rcpf(1.0f + e);
}
__device__ __forceinline__ float fast_tanh(float x) {
  float e = __builtin_amdgcn_exp2f(x * -2.88539008177792681472f);
  return 2.0f * __builtin_amdgcn_rcpf(1.0f + e) - 1.0f;
}

// ---------------- small prep kernels ----------------
__global__ void zero_flags(int* __restrict__ f, int n) {
  int i = blockIdx.x * 256 + threadIdx.x;
  if (i < n) f[i] = 0;
}

__global__ void ctx_mean(const float* __restrict__ c, float* __restrict__ ctx) {
  int b = blockIdx.x;
  for (int d = threadIdx.x; d < D_; d += 256) {
    float s = 0.f;
    #pragma unroll
    for (int n = 0; n < 16; ++n) s += c[((size_t)b * 16 + n) * D_ + d];
    ctx[b * D_ + d] = s * (1.0f / 16.0f);
  }
}

__global__ void h0_compute(const float* __restrict__ ctx, const float* __restrict__ w,
                           const float* __restrict__ bias, float* __restrict__ h0l) {
  int o = blockIdx.x * 256 + threadIdx.x;   // 16384 outputs
  int b = o >> 11, row = o & 2047;
  float s = bias[row];
  const float* cw = w + (size_t)row * D_;
  const float* cb = ctx + b * D_;
  for (int d = 0; d < D_; ++d) s += cb[d] * cw[d];
  int layer = row >> 10, u = row & 1023;
  h0l[((size_t)layer * 8 + b) * 1024 + u] = s;
}

__global__ void gather_embed(const int* __restrict__ seq, const float* __restrict__ emb,
                             unsigned short* __restrict__ x) {
  int r = blockIdx.x;                       // 0..4095 = b*512+s
  int idx = seq[r];
  float4 v = ((const float4*)(emb + (size_t)idx * H_))[threadIdx.x];
  ushort4 o;
  o.x = f2bf(v.x); o.y = f2bf(v.y); o.z = f2bf(v.z); o.w = f2bf(v.w);
  ((ushort4*)(x + (size_t)r * H_))[threadIdx.x] = o;
}

__global__ void f32_to_bf16(const float* __restrict__ in, unsigned short* __restrict__ outp, long n4) {
  long i = blockIdx.x * (long)blockDim.x + threadIdx.x;
  long stride = (long)gridDim.x * blockDim.x;
  for (; i < n4; i += stride) {
    float4 v = ((const float4*)in)[i];
    ushort4 o;
    o.x = f2bf(v.x); o.y = f2bf(v.y); o.z = f2bf(v.z); o.w = f2bf(v.w);
    ((ushort4*)outp)[i] = o;
  }
}

// ---------------- bf16 MFMA GEMM: C[M,N] = A[M,K] * B[N,K]^T + bias[N] ----------------
// M%128==0, N%128==0, K%32==0. 256 threads, 4 waves as 2x2 of 64x64.
__global__ __launch_bounds__(256) void gemm_bt_bf16(
    const unsigned short* __restrict__ A, const unsigned short* __restrict__ B,
    float* __restrict__ C, const float* __restrict__ bias,
    int M, int N, int K)
{
  __shared__ __align__(16) unsigned short As[128 * 32];
  __shared__ __align__(16) unsigned short Bs[128 * 32];
  const int tid = threadIdx.x;
  const int l = tid & 63;
  const int w = tid >> 6;
  const int wr = w >> 1, wc = w & 1;
  const long row0 = (long)blockIdx.y * 128;
  const long col0 = (long)blockIdx.x * 128;

  f32x4_t acc[4][4];
  #pragma unroll
  for (int m = 0; m < 4; ++m)
    #pragma unroll
    for (int n = 0; n < 4; ++n) acc[m][n] = (f32x4_t)0.0f;

  const int sr = tid >> 2;            // staging row (0..63)
  const int sc = (tid & 3) << 3;      // staging col (bf16 elems)

  for (int kt = 0; kt < K; kt += 32) {
    __syncthreads();
    uint4 a0 = *(const uint4*)&A[(row0 + sr) * K + kt + sc];
    uint4 a1 = *(const uint4*)&A[(row0 + sr + 64) * K + kt + sc];
    uint4 b0 = *(const uint4*)&B[(col0 + sr) * K + kt + sc];
    uint4 b1 = *(const uint4*)&B[(col0 + sr + 64) * K + kt + sc];
    ((uint4*)As)[tid]       = a0;
    ((uint4*)As)[tid + 256] = a1;
    ((uint4*)Bs)[tid]       = b0;
    ((uint4*)Bs)[tid + 256] = b1;
    __syncthreads();

    bf16x8_t af[4], bfr[4];
    #pragma unroll
    for (int m = 0; m < 4; ++m)
      af[m] = *(const bf16x8_t*)&As[(wr * 64 + m * 16 + (l & 15)) * 32 + (l >> 4) * 8];
    #pragma unroll
    for (int n = 0; n < 4; ++n)
      bfr[n] = *(const bf16x8_t*)&Bs[(wc * 64 + n * 16 + (l & 15)) * 32 + (l >> 4) * 8];
    #pragma unroll
    for (int m = 0; m < 4; ++m)
      #pragma unroll
      for (int n = 0; n < 4; ++n)
        acc[m][n] = __builtin_amdgcn_mfma_f32_16x16x32_bf16(af[m], bfr[n], acc[m][n], 0, 0, 0);
  }

  #pragma unroll
  for (int n = 0; n < 4; ++n) {
    const long col = col0 + wc * 64 + n * 16 + (l & 15);
    const float bv = bias[col];
    #pragma unroll
    for (int m = 0; m < 4; ++m) {
      const long rbase = row0 + wr * 64 + m * 16 + ((l >> 4) << 2);
      #pragma unroll
      for (int v = 0; v < 4; ++v)
        C[(rbase + v) * (long)N + col] = acc[m][n][v] + bv;
    }
  }
}

// ---------------- persistent GRU layer ----------------
// 128 blocks x 256 threads. Block g owns hidden units j0=g*8 .. j0+7 (rows j,1024+j,2048+j of w_hh).
// fp32 weights in LDS (96KB) + staged h (32KB) = 128KiB exactly.
__global__ __launch_bounds__(256) void gru_layer(
    const float* __restrict__ xg,      // [8,512,3072] incl. b_ih
    const float* __restrict__ w_hh,    // [3072,1024]
    const float* __restrict__ b_hh,    // [3072]
    const float* __restrict__ h0,      // [8,1024]
    unsigned short* __restrict__ y,    // [8,512,1024] bf16
    float* __restrict__ hbuf,          // [2][8][1024]
    int* __restrict__ flags)           // [128*32]
{
  __shared__ __align__(16) float wlds[24 * 1024];
  __shared__ __align__(16) float hlds[8 * 1024];
  const int tid = threadIdx.x;
  const int blk = blockIdx.x;
  const int j0 = blk * 8;

  // load weight rows (r0..r7, z0..z7, n0..n7 for units j0..j0+7)
  for (int idx = tid; idx < 24 * 1024; idx += 256) {
    int L = idx >> 10, k = idx & 1023;
    int grow = (L >> 3) * 1024 + j0 + (L & 7);
    wlds[idx] = w_hh[(size_t)grow * 1024 + k];
  }

  const int b = tid >> 5;         // batch 0..7 (32-lane group)
  const int lane = tid & 31;
  const int gbase = tid & 32;     // group base within wave for shfl

  float bval = 0.f;
  if (lane < 24) bval = b_hh[(lane >> 3) * 1024 + j0 + (lane & 7)];

  for (int t = 0; t < S_; ++t) {
    const float* hsrc = (t == 0) ? h0 : (hbuf + (t & 1) * 8192);
    float* hdst = hbuf + ((t + 1) & 1) * 8192;

    __syncthreads();   // covers weight load (t=0) and prior-iter LDS reads
    for (int i = tid; i < 2048; i += 256)
      ((float4*)hlds)[i] = ((const float4*)hsrc)[i];
    __syncthreads();

    // fetch this step's input-gate values early (overlaps FMA)
    float xv = 0.f;
    if (lane < 24)
      xv = xg[((size_t)(b * S_ + t)) * G3H + (lane >> 3) * 1024 + j0 + (lane & 7)];
    float xvb = (lane < 16) ? xv + bval : xv;   // fold b_hh into r,z pre-activations

    float acc[24];
    #pragma unroll
    for (int L = 0; L < 24; ++L) acc[L] = 0.f;
    const float4* h4p = (const float4*)(hlds + b * 1024);
    const float4* w4p = (const float4*)wlds;
    #pragma unroll
    for (int i = 0; i < 8; ++i) {
      float4 h4 = h4p[lane + 32 * i];
      #pragma unroll
      for (int L = 0; L < 24; ++L) {
        float4 w4 = w4p[L * 256 + lane + 32 * i];
        acc[L] = fmaf(w4.x, h4.x, fmaf(w4.y, h4.y, fmaf(w4.z, h4.z, fmaf(w4.w, h4.w, acc[L]))));
      }
    }
    // butterfly reduce over the 32-lane group
    #pragma unroll
    for (int L = 0; L < 24; ++L) {
      float v = acc[L];
      v += __shfl_xor(v, 1);
      v += __shfl_xor(v, 2);
      v += __shfl_xor(v, 4);
      v += __shfl_xor(v, 8);
      v += __shfl_xor(v, 16);
      acc[L] = v;
    }
    // gates (computed redundantly by all 32 lanes; static acc indices)
    #pragma unroll
    for (int u = 0; u < 8; ++u) {
      float xr = __shfl(xvb, gbase + u);
      float xz = __shfl(xvb, gbase + 8 + u);
      float xn = __shfl(xvb, gbase + 16 + u);
      float bn = __shfl(bval, gbase + 16 + u);
      float r = fast_sigmoid(xr + acc[u]);
      float z = fast_sigmoid(xz + acc[8 + u]);
      float n = fast_tanh(xn + r * (acc[16 + u] + bn));
      float hprev = hlds[b * 1024 + j0 + u];
      float hnew = (1.0f - z) * n + z * hprev;
      if (lane == u) {
        hdst[b * 1024 + j0 + u] = hnew;
        y[((size_t)(b * S_ + t)) * H_ + j0 + u] = f2bf(hnew);
      }
    }
    // inter-block barrier: per-block release slot + acquire polling
    __syncthreads();
    if (tid == 0) {
      __threadfence();
      __hip_atomic_store(&flags[blk * 32], t + 1, __ATOMIC_RELEASE, __HIP_MEMORY_SCOPE_AGENT);
    }
    if (tid < GRU_BLOCKS) {
      while (__hip_atomic_load(&flags[tid * 32], __ATOMIC_ACQUIRE, __HIP_MEMORY_SCOPE_AGENT) < t + 1)
        __builtin_amdgcn_s_sleep(1);
    }
  }
}

// ---------------- launch ----------------
extern "C" void kernel_launch(void* const* d_in, const int* in_sizes, int n_in,
                              void* d_out, int out_size, void* d_ws, size_t ws_size,
                              hipStream_t stream) {
  (void)in_sizes; (void)n_in; (void)out_size; (void)ws_size;
  const float* concepts = (const float*)d_in[0];
  const int*   seq      = (const int*)d_in[1];
  const float* emb      = (const float*)d_in[2];
  const float* w_ih     = (const float*)d_in[3];
  const float* w_hh     = (const float*)d_in[4];
  const float* b_ih     = (const float*)d_in[5];
  const float* b_hh     = (const float*)d_in[6];
  const float* fc_w     = (const float*)d_in[7];
  const float* fc_b     = (const float*)d_in[8];
  const float* c2h_w    = (const float*)d_in[9];
  const float* c2h_b    = (const float*)d_in[10];
  float* out = (float*)d_out;

  char* ws = (char*)d_ws;
  size_t off = 0;
  auto alloc = [&](size_t bytes) {
    char* p = ws + off;
    off += (bytes + 255) & ~(size_t)255;
    return p;
  };
  unsigned short* xy   = (unsigned short*)alloc((size_t)B_ * S_ * H_ * 2);   // x bf16, reused as y1/y2
  float*          xg   = (float*)alloc((size_t)B_ * S_ * G3H * 4);           // input gates (both layers)
  unsigned short* wihb = (unsigned short*)alloc((size_t)2 * G3H * H_ * 2);
  unsigned short* fcwb = (unsigned short*)alloc((size_t)V_ * H_ * 2);
  float*          ctx  = (float*)alloc((size_t)B_ * D_ * 4);
  float*          h0l  = (float*)alloc((size_t)2 * B_ * H_ * 4);
  float*          hbuf = (float*)alloc((size_t)2 * B_ * H_ * 4);
  int*            flags= (int*)alloc((size_t)2 * GRU_BLOCKS * 32 * 4);

  zero_flags<<<dim3(32), dim3(256), 0, stream>>>(flags, 2 * GRU_BLOCKS * 32);
  ctx_mean<<<dim3(8), dim3(256), 0, stream>>>(concepts, ctx);
  h0_compute<<<dim3(64), dim3(256), 0, stream>>>(ctx, c2h_w, c2h_b, h0l);
  gather_embed<<<dim3(B_ * S_), dim3(256), 0, stream>>>(seq, emb, xy);
  f32_to_bf16<<<dim3(1024), dim3(256), 0, stream>>>(w_ih, wihb, (long)2 * G3H * H_ / 4);
  f32_to_bf16<<<dim3(2048), dim3(256), 0, stream>>>(fc_w, fcwb, (long)V_ * H_ / 4);

  // layer 0
  gemm_bt_bf16<<<dim3(G3H / 128, (B_ * S_) / 128), dim3(256), 0, stream>>>(
      xy, wihb, xg, b_ih, B_ * S_, G3H, H_);
  gru_layer<<<dim3(GRU_BLOCKS), dim3(256), 0, stream>>>(
      xg, w_hh, b_hh, h0l, xy, hbuf, flags);

  // layer 1
  gemm_bt_bf16<<<dim3(G3H / 128, (B_ * S_) / 128), dim3(256), 0, stream>>>(
      xy, wihb + (size_t)G3H * H_, xg, b_ih + G3H, B_ * S_, G3H, H_);
  gru_layer<<<dim3(GRU_BLOCKS), dim3(256), 0, stream>>>(
      xg, w_hh + (size_t)G3H * H_, b_hh + G3H, h0l + (size_t)B_ * H_, xy, hbuf,
      flags + GRU_BLOCKS * 32);

  // logits
  gemm_bt_bf16<<<dim3(V_ / 128, (B_ * S_) / 128), dim3(256), 0, stream>>>(
      xy, fcwb, out, fc_b, B_ * S_, V_, H_);
}

// Round 2
// 7859.888 us; speedup vs baseline: 2.2018x; 2.2018x over previous
//
#include <hip/hip_runtime.h>
#include <hip/hip_bf16.h>
#include <stdint.h>

#define B_ 8
#define S_ 512
#define H_ 1024
#define V_ 32000
#define D_ 768
#define G3H (3*H_)
#define GRU_BLOCKS 128

typedef __bf16 bf16x8_t __attribute__((ext_vector_type(8)));
typedef float f32x4_t __attribute__((ext_vector_type(4)));

__device__ __forceinline__ unsigned short f2bf(float f) {
  unsigned int u = __float_as_uint(f);
  u += 0x7fffu + ((u >> 16) & 1u);      // RNE
  return (unsigned short)(u >> 16);
}
__device__ __forceinline__ float fast_sigmoid(float x) {
  float e = __builtin_amdgcn_exp2f(x * -1.44269504088896340736f);
  return __builtin_amdgcn_rcpf(1.0f + e);
}
__device__ __forceinline__ float fast_tanh(float x) {
  float e = __builtin_amdgcn_exp2f(x * -2.88539008177792681472f);
  return 2.0f * __builtin_amdgcn_rcpf(1.0f + e) - 1.0f;
}

// ---------------- small prep kernels ----------------
__global__ void zero_flags(int* __restrict__ f, int n) {
  int i = blockIdx.x * 256 + threadIdx.x;
  if (i < n) f[i] = 0;
}

__global__ void ctx_mean(const float* __restrict__ c, float* __restrict__ ctx) {
  int b = blockIdx.x;
  for (int d = threadIdx.x; d < D_; d += 256) {
    float s = 0.f;
    #pragma unroll
    for (int n = 0; n < 16; ++n) s += c[((size_t)b * 16 + n) * D_ + d];
    ctx[b * D_ + d] = s * (1.0f / 16.0f);
  }
}

__global__ void h0_compute(const float* __restrict__ ctx, const float* __restrict__ w,
                           const float* __restrict__ bias, float* __restrict__ h0l) {
  int o = blockIdx.x * 256 + threadIdx.x;   // 16384 outputs
  int b = o >> 11, row = o & 2047;
  float s = bias[row];
  const float* cw = w + (size_t)row * D_;
  const float* cb = ctx + b * D_;
  for (int d = 0; d < D_; ++d) s += cb[d] * cw[d];
  int layer = row >> 10, u = row & 1023;
  h0l[((size_t)layer * 8 + b) * 1024 + u] = s;
}

__global__ void gather_embed(const int* __restrict__ seq, const float* __restrict__ emb,
                             unsigned short* __restrict__ x) {
  int r = blockIdx.x;                       // 0..4095 = b*512+s
  int idx = seq[r];
  float4 v = ((const float4*)(emb + (size_t)idx * H_))[threadIdx.x];
  ushort4 o;
  o.x = f2bf(v.x); o.y = f2bf(v.y); o.z = f2bf(v.z); o.w = f2bf(v.w);
  ((ushort4*)(x + (size_t)r * H_))[threadIdx.x] = o;
}

__global__ void f32_to_bf16(const float* __restrict__ in, unsigned short* __restrict__ outp, long n4) {
  long i = blockIdx.x * (long)blockDim.x + threadIdx.x;
  long stride = (long)gridDim.x * blockDim.x;
  for (; i < n4; i += stride) {
    float4 v = ((const float4*)in)[i];
    ushort4 o;
    o.x = f2bf(v.x); o.y = f2bf(v.y); o.z = f2bf(v.z); o.w = f2bf(v.w);
    ((ushort4*)outp)[i] = o;
  }
}

// ---------------- bf16 MFMA GEMM: C[M,N] = A[M,K] * B[N,K]^T + bias[N] ----------------
__global__ __launch_bounds__(256) void gemm_bt_bf16(
    const unsigned short* __restrict__ A, const unsigned short* __restrict__ B,
    float* __restrict__ C, const float* __restrict__ bias,
    int M, int N, int K)
{
  __shared__ __align__(16) unsigned short As[128 * 32];
  __shared__ __align__(16) unsigned short Bs[128 * 32];
  const int tid = threadIdx.x;
  const int l = tid & 63;
  const int w = tid >> 6;
  const int wr = w >> 1, wc = w & 1;
  const long row0 = (long)blockIdx.y * 128;
  const long col0 = (long)blockIdx.x * 128;

  f32x4_t acc[4][4];
  #pragma unroll
  for (int m = 0; m < 4; ++m)
    #pragma unroll
    for (int n = 0; n < 4; ++n) acc[m][n] = (f32x4_t)0.0f;

  const int sr = tid >> 2;
  const int sc = (tid & 3) << 3;

  for (int kt = 0; kt < K; kt += 32) {
    __syncthreads();
    uint4 a0 = *(const uint4*)&A[(row0 + sr) * K + kt + sc];
    uint4 a1 = *(const uint4*)&A[(row0 + sr + 64) * K + kt + sc];
    uint4 b0 = *(const uint4*)&B[(col0 + sr) * K + kt + sc];
    uint4 b1 = *(const uint4*)&B[(col0 + sr + 64) * K + kt + sc];
    ((uint4*)As)[tid]       = a0;
    ((uint4*)As)[tid + 256] = a1;
    ((uint4*)Bs)[tid]       = b0;
    ((uint4*)Bs)[tid + 256] = b1;
    __syncthreads();

    bf16x8_t af[4], bfr[4];
    #pragma unroll
    for (int m = 0; m < 4; ++m)
      af[m] = *(const bf16x8_t*)&As[(wr * 64 + m * 16 + (l & 15)) * 32 + (l >> 4) * 8];
    #pragma unroll
    for (int n = 0; n < 4; ++n)
      bfr[n] = *(const bf16x8_t*)&Bs[(wc * 64 + n * 16 + (l & 15)) * 32 + (l >> 4) * 8];
    #pragma unroll
    for (int m = 0; m < 4; ++m)
      #pragma unroll
      for (int n = 0; n < 4; ++n)
        acc[m][n] = __builtin_amdgcn_mfma_f32_16x16x32_bf16(af[m], bfr[n], acc[m][n], 0, 0, 0);
  }

  #pragma unroll
  for (int n = 0; n < 4; ++n) {
    const long col = col0 + wc * 64 + n * 16 + (l & 15);
    const float bv = bias[col];
    #pragma unroll
    for (int m = 0; m < 4; ++m) {
      const long rbase = row0 + wr * 64 + m * 16 + ((l >> 4) << 2);
      #pragma unroll
      for (int v = 0; v < 4; ++v)
        C[(rbase + v) * (long)N + col] = acc[m][n][v] + bv;
    }
  }
}

// ---------------- persistent GRU layer ----------------
// 128 blocks x 256 threads. Block g owns hidden units j0=g*8 .. j0+7.
// fp32 weights in LDS (96KB). h broadcast via L2-bypassing (sc0 sc1) loads/stores:
// no cache-maintenance ops anywhere in the step loop (the R1 killer).
__global__ __launch_bounds__(256) void gru_layer(
    const float* __restrict__ xg,      // [8,512,3072] incl. b_ih
    const float* __restrict__ w_hh,    // [3072,1024]
    const float* __restrict__ b_hh,    // [3072]
    const float* __restrict__ h0,      // [8,1024]
    unsigned short* __restrict__ y,    // [8,512,1024] bf16
    float* __restrict__ hbuf,          // [2][8][1024]
    int* __restrict__ flags)           // [128*32]
{
  __shared__ __align__(16) float wlds[24 * 1024];
  const int tid = threadIdx.x;
  const int blk = blockIdx.x;
  const int j0 = blk * 8;

  for (int idx = tid; idx < 24 * 1024; idx += 256) {
    int L = idx >> 10, k = idx & 1023;
    int grow = (L >> 3) * 1024 + j0 + (L & 7);
    wlds[idx] = w_hh[(size_t)grow * 1024 + k];
  }
  __syncthreads();

  const int b = tid >> 5;         // batch 0..7 (32-lane group)
  const int lane = tid & 31;
  const int gbase = tid & 32;     // group base within wave for shfl

  float bval = 0.f;
  if (lane < 24) bval = b_hh[(lane >> 3) * 1024 + j0 + (lane & 7)];

  const float4* w4p = (const float4*)wlds;

  for (int t = 0; t < S_; ++t) {
    const float* hsrc = (t == 0) ? h0 : (hbuf + (t & 1) * 8192);
    float* hdst = hbuf + ((t + 1) & 1) * 8192;

    // --- h broadcast: straight to registers, bypassing L1/L2 ---
    const float* hb = hsrc + b * 1024;
    f32x4_t h4[8];
    #pragma unroll
    for (int i = 0; i < 8; ++i)
      asm volatile("global_load_dwordx4 %0, %1, off sc0 sc1"
                   : "=v"(h4[i]) : "v"(hb + 4 * (lane + 32 * i)) : "memory");
    float hp;   // lane u (u<8) ends up holding h_prev[j0+u]
    asm volatile("global_load_dword %0, %1, off sc0 sc1"
                 : "=v"(hp) : "v"(hb + j0 + (lane & 7)) : "memory");
    float xv = 0.f;
    if (lane < 24)
      xv = xg[((size_t)(b * S_ + t)) * G3H + (lane >> 3) * 1024 + j0 + (lane & 7)];
    asm volatile("s_waitcnt vmcnt(0)" ::: "memory");
    __builtin_amdgcn_sched_barrier(0);

    float xvb = (lane < 16) ? xv + bval : xv;   // fold b_hh into r,z pre-activations

    float acc[24];
    #pragma unroll
    for (int L = 0; L < 24; ++L) acc[L] = 0.f;
    #pragma unroll
    for (int i = 0; i < 8; ++i) {
      #pragma unroll
      for (int L = 0; L < 24; ++L) {
        float4 w4 = w4p[L * 256 + lane + 32 * i];
        acc[L] = fmaf(w4.x, h4[i][0], fmaf(w4.y, h4[i][1],
                 fmaf(w4.z, h4[i][2], fmaf(w4.w, h4[i][3], acc[L]))));
      }
    }
    // butterfly reduce over the 32-lane group
    #pragma unroll
    for (int L = 0; L < 24; ++L) {
      float v = acc[L];
      v += __shfl_xor(v, 1);
      v += __shfl_xor(v, 2);
      v += __shfl_xor(v, 4);
      v += __shfl_xor(v, 8);
      v += __shfl_xor(v, 16);
      acc[L] = v;
    }
    // gates (redundant across lanes; lane==u commits unit u)
    #pragma unroll
    for (int u = 0; u < 8; ++u) {
      float xr = __shfl(xvb, gbase + u);
      float xz = __shfl(xvb, gbase + 8 + u);
      float xn = __shfl(xvb, gbase + 16 + u);
      float bn = __shfl(bval, gbase + 16 + u);
      float hprev = __shfl(hp, gbase + u);
      float r = fast_sigmoid(xr + acc[u]);
      float z = fast_sigmoid(xz + acc[8 + u]);
      float n = fast_tanh(xn + r * (acc[16 + u] + bn));
      float hnew = (1.0f - z) * n + z * hprev;
      if (lane == u) {
        __hip_atomic_store(&hdst[b * 1024 + j0 + u], hnew,
                           __ATOMIC_RELAXED, __HIP_MEMORY_SCOPE_AGENT);
        y[((size_t)(b * S_ + t)) * H_ + j0 + u] = f2bf(hnew);
      }
    }
    // inter-block barrier, no cache maintenance:
    // __syncthreads drains each wave's vmcnt (stores are write-through sc0sc1,
    // so retired == globally visible), then relaxed flag store + relaxed poll.
    __syncthreads();
    if (tid == 0)
      __hip_atomic_store(&flags[blk * 32], t + 1,
                         __ATOMIC_RELAXED, __HIP_MEMORY_SCOPE_AGENT);
    if (tid < GRU_BLOCKS) {
      while (__hip_atomic_load(&flags[tid * 32],
                               __ATOMIC_RELAXED, __HIP_MEMORY_SCOPE_AGENT) < t + 1)
        __builtin_amdgcn_s_sleep(1);
    }
    __syncthreads();
  }
}

// ---------------- launch ----------------
extern "C" void kernel_launch(void* const* d_in, const int* in_sizes, int n_in,
                              void* d_out, int out_size, void* d_ws, size_t ws_size,
                              hipStream_t stream) {
  (void)in_sizes; (void)n_in; (void)out_size; (void)ws_size;
  const float* concepts = (const float*)d_in[0];
  const int*   seq      = (const int*)d_in[1];
  const float* emb      = (const float*)d_in[2];
  const float* w_ih     = (const float*)d_in[3];
  const float* w_hh     = (const float*)d_in[4];
  const float* b_ih     = (const float*)d_in[5];
  const float* b_hh     = (const float*)d_in[6];
  const float* fc_w     = (const float*)d_in[7];
  const float* fc_b     = (const float*)d_in[8];
  const float* c2h_w    = (const float*)d_in[9];
  const float* c2h_b    = (const float*)d_in[10];
  float* out = (float*)d_out;

  char* ws = (char*)d_ws;
  size_t off = 0;
  auto alloc = [&](size_t bytes) {
    char* p = ws + off;
    off += (bytes + 255) & ~(size_t)255;
    return p;
  };
  unsigned short* xy   = (unsigned short*)alloc((size_t)B_ * S_ * H_ * 2);
  float*          xg   = (float*)alloc((size_t)B_ * S_ * G3H * 4);
  unsigned short* wihb = (unsigned short*)alloc((size_t)2 * G3H * H_ * 2);
  unsigned short* fcwb = (unsigned short*)alloc((size_t)V_ * H_ * 2);
  float*          ctx  = (float*)alloc((size_t)B_ * D_ * 4);
  float*          h0l  = (float*)alloc((size_t)2 * B_ * H_ * 4);
  float*          hbuf = (float*)alloc((size_t)2 * B_ * H_ * 4);
  int*            flags= (int*)alloc((size_t)2 * GRU_BLOCKS * 32 * 4);

  zero_flags<<<dim3(32), dim3(256), 0, stream>>>(flags, 2 * GRU_BLOCKS * 32);
  ctx_mean<<<dim3(8), dim3(256), 0, stream>>>(concepts, ctx);
  h0_compute<<<dim3(64), dim3(256), 0, stream>>>(ctx, c2h_w, c2h_b, h0l);
  gather_embed<<<dim3(B_ * S_), dim3(256), 0, stream>>>(seq, emb, xy);
  f32_to_bf16<<<dim3(1024), dim3(256), 0, stream>>>(w_ih, wihb, (long)2 * G3H * H_ / 4);
  f32_to_bf16<<<dim3(2048), dim3(256), 0, stream>>>(fc_w, fcwb, (long)V_ * H_ / 4);

  // layer 0
  gemm_bt_bf16<<<dim3(G3H / 128, (B_ * S_) / 128), dim3(256), 0, stream>>>(
      xy, wihb, xg, b_ih, B_ * S_, G3H, H_);
  gru_layer<<<dim3(GRU_BLOCKS), dim3(256), 0, stream>>>(
      xg, w_hh, b_hh, h0l, xy, hbuf, flags);

  // layer 1
  gemm_bt_bf16<<<dim3(G3H / 128, (B_ * S_) / 128), dim3(256), 0, stream>>>(
      xy, wihb + (size_t)G3H * H_, xg, b_ih + G3H, B_ * S_, G3H, H_);
  gru_layer<<<dim3(GRU_BLOCKS), dim3(256), 0, stream>>>(
      xg, w_hh + (size_t)G3H * H_, b_hh + G3H, h0l + (size_t)B_ * H_, xy, hbuf,
      flags + GRU_BLOCKS * 32);

  // logits
  gemm_bt_bf16<<<dim3(V_ / 128, (B_ * S_) / 128), dim3(256), 0, stream>>>(
      xy, fcwb, out, fc_b, B_ * S_, V_, H_);
}

// Round 3
// 3728.651 us; speedup vs baseline: 4.6414x; 2.1080x over previous
//
#include <hip/hip_runtime.h>
#include <hip/hip_bf16.h>
#include <stdint.h>

#define B_ 8
#define S_ 512
#define H_ 1024
#define V_ 32000
#define D_ 768
#define G3H (3*H_)
#define GRU_BLOCKS 128

typedef __bf16 bf16x8_t __attribute__((ext_vector_type(8)));
typedef float f32x4_t __attribute__((ext_vector_type(4)));

__device__ __forceinline__ unsigned short f2bf(float f) {
  unsigned int u = __float_as_uint(f);
  u += 0x7fffu + ((u >> 16) & 1u);      // RNE
  return (unsigned short)(u >> 16);
}
__device__ __forceinline__ float fast_sigmoid(float x) {
  float e = __builtin_amdgcn_exp2f(x * -1.44269504088896340736f);
  return __builtin_amdgcn_rcpf(1.0f + e);
}
__device__ __forceinline__ float fast_tanh(float x) {
  float e = __builtin_amdgcn_exp2f(x * -2.88539008177792681472f);
  return 2.0f * __builtin_amdgcn_rcpf(1.0f + e) - 1.0f;
}

// ---------------- small prep kernels ----------------
__global__ void zero_buf(uint4* __restrict__ p, int n) {
  int i = blockIdx.x * 256 + threadIdx.x;
  if (i < n) p[i] = uint4{0, 0, 0, 0};
}

__global__ void ctx_mean(const float* __restrict__ c, float* __restrict__ ctx) {
  int b = blockIdx.x;
  for (int d = threadIdx.x; d < D_; d += 256) {
    float s = 0.f;
    #pragma unroll
    for (int n = 0; n < 16; ++n) s += c[((size_t)b * 16 + n) * D_ + d];
    ctx[b * D_ + d] = s * (1.0f / 16.0f);
  }
}

// writes fp32 h0 (for in-register h_prev) AND bf16 h0 into hb slot 0 (for broadcast)
__global__ void h0_compute(const float* __restrict__ ctx, const float* __restrict__ w,
                           const float* __restrict__ bias, float* __restrict__ h0l,
                           unsigned short* __restrict__ hb) {
  int o = blockIdx.x * 256 + threadIdx.x;   // 16384 outputs
  int b = o >> 11, row = o & 2047;
  float s = bias[row];
  const float* cw = w + (size_t)row * D_;
  const float* cb = ctx + b * D_;
  for (int d = 0; d < D_; ++d) s += cb[d] * cw[d];
  int layer = row >> 10, u = row & 1023;
  h0l[((size_t)layer * 8 + b) * 1024 + u] = s;
  hb[(size_t)layer * 32768 + b * 1024 + u] = f2bf(s);   // slot 0 of this layer's ping-pong
}

__global__ void gather_embed(const int* __restrict__ seq, const float* __restrict__ emb,
                             unsigned short* __restrict__ x) {
  int r = blockIdx.x;                       // 0..4095 = b*512+s
  int idx = seq[r];
  float4 v = ((const float4*)(emb + (size_t)idx * H_))[threadIdx.x];
  ushort4 o;
  o.x = f2bf(v.x); o.y = f2bf(v.y); o.z = f2bf(v.z); o.w = f2bf(v.w);
  ((ushort4*)(x + (size_t)r * H_))[threadIdx.x] = o;
}

__global__ void f32_to_bf16(const float* __restrict__ in, unsigned short* __restrict__ outp, long n4) {
  long i = blockIdx.x * (long)blockDim.x + threadIdx.x;
  long stride = (long)gridDim.x * blockDim.x;
  for (; i < n4; i += stride) {
    float4 v = ((const float4*)in)[i];
    ushort4 o;
    o.x = f2bf(v.x); o.y = f2bf(v.y); o.z = f2bf(v.z); o.w = f2bf(v.w);
    ((ushort4*)outp)[i] = o;
  }
}

// ---------------- bf16 MFMA GEMM: C[M,N] = A[M,K] * B[N,K]^T + bias[N] ----------------
__global__ __launch_bounds__(256) void gemm_bt_bf16(
    const unsigned short* __restrict__ A, const unsigned short* __restrict__ B,
    float* __restrict__ C, const float* __restrict__ bias,
    int M, int N, int K)
{
  __shared__ __align__(16) unsigned short As[128 * 32];
  __shared__ __align__(16) unsigned short Bs[128 * 32];
  const int tid = threadIdx.x;
  const int l = tid & 63;
  const int w = tid >> 6;
  const int wr = w >> 1, wc = w & 1;
  const long row0 = (long)blockIdx.y * 128;
  const long col0 = (long)blockIdx.x * 128;

  f32x4_t acc[4][4];
  #pragma unroll
  for (int m = 0; m < 4; ++m)
    #pragma unroll
    for (int n = 0; n < 4; ++n) acc[m][n] = (f32x4_t)0.0f;

  const int sr = tid >> 2;
  const int sc = (tid & 3) << 3;

  for (int kt = 0; kt < K; kt += 32) {
    __syncthreads();
    uint4 a0 = *(const uint4*)&A[(row0 + sr) * K + kt + sc];
    uint4 a1 = *(const uint4*)&A[(row0 + sr + 64) * K + kt + sc];
    uint4 b0 = *(const uint4*)&B[(col0 + sr) * K + kt + sc];
    uint4 b1 = *(const uint4*)&B[(col0 + sr + 64) * K + kt + sc];
    ((uint4*)As)[tid]       = a0;
    ((uint4*)As)[tid + 256] = a1;
    ((uint4*)Bs)[tid]       = b0;
    ((uint4*)Bs)[tid + 256] = b1;
    __syncthreads();

    bf16x8_t af[4], bfr[4];
    #pragma unroll
    for (int m = 0; m < 4; ++m)
      af[m] = *(const bf16x8_t*)&As[(wr * 64 + m * 16 + (l & 15)) * 32 + (l >> 4) * 8];
    #pragma unroll
    for (int n = 0; n < 4; ++n)
      bfr[n] = *(const bf16x8_t*)&Bs[(wc * 64 + n * 16 + (l & 15)) * 32 + (l >> 4) * 8];
    #pragma unroll
    for (int m = 0; m < 4; ++m)
      #pragma unroll
      for (int n = 0; n < 4; ++n)
        acc[m][n] = __builtin_amdgcn_mfma_f32_16x16x32_bf16(af[m], bfr[n], acc[m][n], 0, 0, 0);
  }

  #pragma unroll
  for (int n = 0; n < 4; ++n) {
    const long col = col0 + wc * 64 + n * 16 + (l & 15);
    const float bv = bias[col];
    #pragma unroll
    for (int m = 0; m < 4; ++m) {
      const long rbase = row0 + wr * 64 + m * 16 + ((l >> 4) << 2);
      #pragma unroll
      for (int v = 0; v < 4; ++v)
        C[(rbase + v) * (long)N + col] = acc[m][n][v] + bv;
    }
  }
}

// ---------------- persistent GRU layer (MFMA matvec, register weights) ----------------
// 128 blocks x 256 threads. Block g owns hidden units j0=g*8..j0+7 (24 W-rows).
// K=1024 split across 4 waves (256 each). Weights live in VGPRs as bf16 A-frags.
// h broadcast is bf16 [16][1024] ping-pong (rows 8..15 stay zero), sc0sc1 bypass.
__global__ __launch_bounds__(256) void gru_layer(
    const float* __restrict__ xg,      // [8,512,3072] incl. b_ih
    const float* __restrict__ w_hh,    // [3072,1024] (layer slice)
    const float* __restrict__ b_hh,    // [3072] (layer slice)
    const float* __restrict__ h0f,     // [8,1024] fp32 (layer slice)
    unsigned short* __restrict__ y,    // [8,512,1024] bf16
    unsigned short* __restrict__ hb,   // [2][16*1024] bf16 ping-pong (layer slice)
    int* __restrict__ flags)           // [128*32]
{
  __shared__ __align__(16) float red[4 * 512];   // 8KB: [wave][tile m][16x16 f32]
  const int tid = threadIdx.x;
  const int blk = blockIdx.x;
  const int j0 = blk * 8;
  const int w = tid >> 6;
  const int l = tid & 63;
  const int l15 = l & 15;
  const int lhi = l >> 4;

  // ---- preload W_hh rows as bf16 A-fragments in registers ----
  // A-frag layout (mirrors gemm_bt_bf16): lane holds A[m*16 + (l&15)][k0 + (l>>4)*8 + j]
  bf16x8_t wf[2][8];
  #pragma unroll
  for (int m = 0; m < 2; ++m) {
    const int idx = m * 16 + l15;          // row within the 24
    const int g = idx >> 3, uu = idx & 7;
    #pragma unroll
    for (int c = 0; c < 8; ++c) {
      f32x4_t v0 = {0.f, 0.f, 0.f, 0.f}, v1 = {0.f, 0.f, 0.f, 0.f};
      if (idx < 24) {
        const float* p = w_hh + (size_t)((g << 10) + j0 + uu) * 1024
                              + (w << 8) + (c << 5) + (lhi << 3);
        v0 = *(const f32x4_t*)p;
        v1 = *(const f32x4_t*)(p + 4);
      }
      bf16x8_t f;
      f[0] = (__bf16)v0[0]; f[1] = (__bf16)v0[1]; f[2] = (__bf16)v0[2]; f[3] = (__bf16)v0[3];
      f[4] = (__bf16)v1[0]; f[5] = (__bf16)v1[1]; f[6] = (__bf16)v1[2]; f[7] = (__bf16)v1[3];
      wf[m][c] = f;
    }
  }

  // ---- per-gate-thread state (tid<64): u = tid&7, b = tid>>3 ----
  const int u = tid & 7;
  const int b = tid >> 3;
  float br = 0.f, bz = 0.f, bn2 = 0.f, hprev = 0.f;
  const float* xgp = nullptr;
  if (tid < 64) {
    br  = b_hh[j0 + u];
    bz  = b_hh[1024 + j0 + u];
    bn2 = b_hh[2048 + j0 + u];
    hprev = h0f[b * 1024 + j0 + u];
    xgp = xg + (size_t)(b * S_) * G3H + j0 + u;
  }

  __syncthreads();

  for (int t = 0; t < S_; ++t) {
    const unsigned short* hsrc = hb + (t & 1) * 16384;
    unsigned short* hdst = hb + ((t + 1) & 1) * 16384;

    // xg loads for this step (normal cached; compiler-tracked)
    float xr = 0.f, xz = 0.f, xn = 0.f;
    if (tid < 64) {
      const float* p = xgp + (size_t)t * G3H;
      xr = p[0]; xz = p[1024]; xn = p[2048];
    }

    // B-frags: h_bf16[batch = l15][k = w*256 + c*32 + lhi*8 ..+7], L2-bypassing
    const unsigned short* hp0 = hsrc + l15 * 1024 + (w << 8) + (lhi << 3);
    f32x4_t hv[8];
    #pragma unroll
    for (int c = 0; c < 8; ++c)
      asm volatile("global_load_dwordx4 %0, %1, off offset:%2 sc0 sc1"
                   : "=v"(hv[c]) : "v"(hp0), "i"(c * 64) : "memory");
    asm volatile("s_waitcnt vmcnt(0)" ::: "memory");
    __builtin_amdgcn_sched_barrier(0);

    f32x4_t a0 = {0.f, 0.f, 0.f, 0.f}, a1 = {0.f, 0.f, 0.f, 0.f};
    #pragma unroll
    for (int c = 0; c < 8; ++c) {
      bf16x8_t hfc = __builtin_bit_cast(bf16x8_t, hv[c]);
      a0 = __builtin_amdgcn_mfma_f32_16x16x32_bf16(wf[0][c], hfc, a0, 0, 0, 0);
      a1 = __builtin_amdgcn_mfma_f32_16x16x32_bf16(wf[1][c], hfc, a1, 0, 0, 0);
    }

    // cross-wave K-reduction via LDS
    *(f32x4_t*)&red[(w << 9) + (l << 2)] = a0;
    *(f32x4_t*)&red[(w << 9) + 256 + (l << 2)] = a1;
    __syncthreads();

    if (tid < 64) {
      // D layout: row = (lane>>4)*4 + reg, col = lane&15(=batch)
      const int base0 = ((((u) >> 2) << 4 | b) << 2) + (u & 3);          // row u      (tile 0)
      const int base1 = ((((8 + u) >> 2) << 4 | b) << 2) + (u & 3);      // row 8+u    (tile 0)
      const int base2 = base0 + 256;                                     // row 16+u   (tile 1)
      float aR = 0.f, aZ = 0.f, aN = 0.f;
      #pragma unroll
      for (int ww = 0; ww < 4; ++ww) {
        aR += red[ww * 512 + base0];
        aZ += red[ww * 512 + base1];
        aN += red[ww * 512 + base2];
      }
      float r = fast_sigmoid(xr + br + aR);
      float z = fast_sigmoid(xz + bz + aZ);
      float n = fast_tanh(xn + r * (aN + bn2));
      hprev = (1.0f - z) * n + z * hprev;
      unsigned short hv16 = f2bf(hprev);
      y[(((size_t)(b * S_ + t)) << 10) + j0 + u] = hv16;   // normal store (next kernel reads)
      asm volatile("global_store_short %0, %1, off sc0 sc1"
                   :: "v"(hdst + b * 1024 + j0 + u), "v"(hv16) : "memory");
    }
    // drain asm stores (compiler can't track them), then barrier, then flag release
    asm volatile("s_waitcnt vmcnt(0)" ::: "memory");
    __syncthreads();
    if (tid == 0)
      __hip_atomic_store(&flags[blk * 32], t + 1,
                         __ATOMIC_RELAXED, __HIP_MEMORY_SCOPE_AGENT);
    if (tid < GRU_BLOCKS) {
      while (__hip_atomic_load(&flags[tid * 32],
                               __ATOMIC_RELAXED, __HIP_MEMORY_SCOPE_AGENT) < t + 1)
        __builtin_amdgcn_s_sleep(1);
    }
    __syncthreads();
  }
}

// ---------------- launch ----------------
extern "C" void kernel_launch(void* const* d_in, const int* in_sizes, int n_in,
                              void* d_out, int out_size, void* d_ws, size_t ws_size,
                              hipStream_t stream) {
  (void)in_sizes; (void)n_in; (void)out_size; (void)ws_size;
  const float* concepts = (const float*)d_in[0];
  const int*   seq      = (const int*)d_in[1];
  const float* emb      = (const float*)d_in[2];
  const float* w_ih     = (const float*)d_in[3];
  const float* w_hh     = (const float*)d_in[4];
  const float* b_ih     = (const float*)d_in[5];
  const float* b_hh     = (const float*)d_in[6];
  const float* fc_w     = (const float*)d_in[7];
  const float* fc_b     = (const float*)d_in[8];
  const float* c2h_w    = (const float*)d_in[9];
  const float* c2h_b    = (const float*)d_in[10];
  float* out = (float*)d_out;

  char* ws = (char*)d_ws;
  size_t off = 0;
  auto alloc = [&](size_t bytes) {
    char* p = ws + off;
    off += (bytes + 255) & ~(size_t)255;
    return p;
  };
  unsigned short* xy   = (unsigned short*)alloc((size_t)B_ * S_ * H_ * 2);
  float*          xg   = (float*)alloc((size_t)B_ * S_ * G3H * 4);
  unsigned short* wihb = (unsigned short*)alloc((size_t)2 * G3H * H_ * 2);
  unsigned short* fcwb = (unsigned short*)alloc((size_t)V_ * H_ * 2);
  float*          ctx  = (float*)alloc((size_t)B_ * D_ * 4);
  float*          h0l  = (float*)alloc((size_t)2 * B_ * H_ * 4);
  unsigned short* hb   = (unsigned short*)alloc((size_t)2 * 2 * 16 * 1024 * 2);  // 128KB
  int*            flags= (int*)alloc((size_t)2 * GRU_BLOCKS * 32 * 4);           // 32KB (contiguous after hb)

  // zero hb (both layers, both slots incl. pad rows 8..15) + flags in one pass
  zero_buf<<<dim3(40), dim3(256), 0, stream>>>((uint4*)hb, (131072 + 32768) / 16);
  ctx_mean<<<dim3(8), dim3(256), 0, stream>>>(concepts, ctx);
  h0_compute<<<dim3(64), dim3(256), 0, stream>>>(ctx, c2h_w, c2h_b, h0l, hb);
  gather_embed<<<dim3(B_ * S_), dim3(256), 0, stream>>>(seq, emb, xy);
  f32_to_bf16<<<dim3(1024), dim3(256), 0, stream>>>(w_ih, wihb, (long)2 * G3H * H_ / 4);
  f32_to_bf16<<<dim3(2048), dim3(256), 0, stream>>>(fc_w, fcwb, (long)V_ * H_ / 4);

  // layer 0
  gemm_bt_bf16<<<dim3(G3H / 128, (B_ * S_) / 128), dim3(256), 0, stream>>>(
      xy, wihb, xg, b_ih, B_ * S_, G3H, H_);
  gru_layer<<<dim3(GRU_BLOCKS), dim3(256), 0, stream>>>(
      xg, w_hh, b_hh, h0l, xy, hb, flags);

  // layer 1
  gemm_bt_bf16<<<dim3(G3H / 128, (B_ * S_) / 128), dim3(256), 0, stream>>>(
      xy, wihb + (size_t)G3H * H_, xg, b_ih + G3H, B_ * S_, G3H, H_);
  gru_layer<<<dim3(GRU_BLOCKS), dim3(256), 0, stream>>>(
      xg, w_hh + (size_t)G3H * H_, b_hh + G3H, h0l + (size_t)B_ * H_, xy,
      hb + 32768, flags + GRU_BLOCKS * 32);

  // logits
  gemm_bt_bf16<<<dim3(V_ / 128, (B_ * S_) / 128), dim3(256), 0, stream>>>(
      xy, fcwb, out, fc_b, B_ * S_, V_, H_);
}

// Round 5
// 2703.345 us; speedup vs baseline: 6.4017x; 1.3793x over previous
//
#include <hip/hip_runtime.h>
#include <hip/hip_bf16.h>
#include <stdint.h>

#define B_ 8
#define S_ 512
#define H_ 1024
#define V_ 32000
#define D_ 768
#define G3H (3*H_)

typedef __bf16 bf16x8_t __attribute__((ext_vector_type(8)));
typedef float f32x4_t __attribute__((ext_vector_type(4)));

__device__ __forceinline__ unsigned short f2bf(float f) {
  unsigned int u = __float_as_uint(f);
  u += 0x7fffu + ((u >> 16) & 1u);      // RNE
  return (unsigned short)(u >> 16);
}
__device__ __forceinline__ float fast_sigmoid(float x) {
  float e = __builtin_amdgcn_exp2f(x * -1.44269504088896340736f);
  return __builtin_amdgcn_rcpf(1.0f + e);
}
__device__ __forceinline__ float fast_tanh(float x) {
  float e = __builtin_amdgcn_exp2f(x * -2.88539008177792681472f);
  return 2.0f * __builtin_amdgcn_rcpf(1.0f + e) - 1.0f;
}

// ---------------- small prep kernels ----------------
__global__ void zero_buf(uint4* __restrict__ p, int n) {
  int i = blockIdx.x * 256 + threadIdx.x;
  if (i < n) p[i] = uint4{0, 0, 0, 0};
}

__global__ void ctx_mean(const float* __restrict__ c, float* __restrict__ ctx) {
  int b = blockIdx.x;
  for (int d = threadIdx.x; d < D_; d += 256) {
    float s = 0.f;
    #pragma unroll
    for (int n = 0; n < 16; ++n) s += c[((size_t)b * 16 + n) * D_ + d];
    ctx[b * D_ + d] = s * (1.0f / 16.0f);
  }
}

// writes fp32 h0 (for in-register h_prev) AND bf16 h0 into each layer's slot 0
__global__ void h0_compute(const float* __restrict__ ctx, const float* __restrict__ w,
                           const float* __restrict__ bias, float* __restrict__ h0l,
                           unsigned short* __restrict__ hb) {
  int o = blockIdx.x * 256 + threadIdx.x;   // 16384 outputs
  int b = o >> 11, row = o & 2047;
  float s = bias[row];
  const float* cw = w + (size_t)row * D_;
  const float* cb = ctx + b * D_;
  for (int d = 0; d < D_; ++d) s += cb[d] * cw[d];
  int layer = row >> 10, u = row & 1023;
  h0l[((size_t)layer * 8 + b) * 1024 + u] = s;
  hb[(size_t)layer * 32768 + b * 1024 + u] = f2bf(s);   // slot 0 of this layer
}

__global__ void gather_embed(const int* __restrict__ seq, const float* __restrict__ emb,
                             unsigned short* __restrict__ x) {
  int r = blockIdx.x;                       // 0..4095 = b*512+s
  int idx = seq[r];
  float4 v = ((const float4*)(emb + (size_t)idx * H_))[threadIdx.x];
  ushort4 o;
  o.x = f2bf(v.x); o.y = f2bf(v.y); o.z = f2bf(v.z); o.w = f2bf(v.w);
  ((ushort4*)(x + (size_t)r * H_))[threadIdx.x] = o;
}

__global__ void f32_to_bf16(const float* __restrict__ in, unsigned short* __restrict__ outp, long n4) {
  long i = blockIdx.x * (long)blockDim.x + threadIdx.x;
  long stride = (long)gridDim.x * blockDim.x;
  for (; i < n4; i += stride) {
    float4 v = ((const float4*)in)[i];
    ushort4 o;
    o.x = f2bf(v.x); o.y = f2bf(v.y); o.z = f2bf(v.z); o.w = f2bf(v.w);
    ((ushort4*)outp)[i] = o;
  }
}

// ---------------- bf16 MFMA GEMM: C[M,N] = A[M,K] * B[N,K]^T + bias[N] ----------------
__global__ __launch_bounds__(256) void gemm_bt_bf16(
    const unsigned short* __restrict__ A, const unsigned short* __restrict__ B,
    float* __restrict__ C, const float* __restrict__ bias,
    int M, int N, int K)
{
  __shared__ __align__(16) unsigned short As[128 * 32];
  __shared__ __align__(16) unsigned short Bs[128 * 32];
  const int tid = threadIdx.x;
  const int l = tid & 63;
  const int w = tid >> 6;
  const int wr = w >> 1, wc = w & 1;
  const long row0 = (long)blockIdx.y * 128;
  const long col0 = (long)blockIdx.x * 128;

  f32x4_t acc[4][4];
  #pragma unroll
  for (int m = 0; m < 4; ++m)
    #pragma unroll
    for (int n = 0; n < 4; ++n) acc[m][n] = (f32x4_t)0.0f;

  const int sr = tid >> 2;
  const int sc = (tid & 3) << 3;

  for (int kt = 0; kt < K; kt += 32) {
    __syncthreads();
    uint4 a0 = *(const uint4*)&A[(row0 + sr) * K + kt + sc];
    uint4 a1 = *(const uint4*)&A[(row0 + sr + 64) * K + kt + sc];
    uint4 b0 = *(const uint4*)&B[(col0 + sr) * K + kt + sc];
    uint4 b1 = *(const uint4*)&B[(col0 + sr + 64) * K + kt + sc];
    ((uint4*)As)[tid]       = a0;
    ((uint4*)As)[tid + 256] = a1;
    ((uint4*)Bs)[tid]       = b0;
    ((uint4*)Bs)[tid + 256] = b1;
    __syncthreads();

    bf16x8_t af[4], bfr[4];
    #pragma unroll
    for (int m = 0; m < 4; ++m)
      af[m] = *(const bf16x8_t*)&As[(wr * 64 + m * 16 + (l & 15)) * 32 + (l >> 4) * 8];
    #pragma unroll
    for (int n = 0; n < 4; ++n)
      bfr[n] = *(const bf16x8_t*)&Bs[(wc * 64 + n * 16 + (l & 15)) * 32 + (l >> 4) * 8];
    #pragma unroll
    for (int m = 0; m < 4; ++m)
      #pragma unroll
      for (int n = 0; n < 4; ++n)
        acc[m][n] = __builtin_amdgcn_mfma_f32_16x16x32_bf16(af[m], bfr[n], acc[m][n], 0, 0, 0);
  }

  #pragma unroll
  for (int n = 0; n < 4; ++n) {
    const long col = col0 + wc * 64 + n * 16 + (l & 15);
    const float bv = bias[col];
    #pragma unroll
    for (int m = 0; m < 4; ++m) {
      const long rbase = row0 + wr * 64 + m * 16 + ((l >> 4) << 2);
      #pragma unroll
      for (int v = 0; v < 4; ++v)
        C[(rbase + v) * (long)N + col] = acc[m][n][v] + bv;
    }
  }
}

// ---------------- fused 2-layer persistent GRU ----------------
// 256 blocks x 256 threads. layer = blk>>7, g = blk&127, units j0=g*8..j0+7.
// Skewed pipeline: epoch e runs layer0 @ t=e and layer1 @ t=e-1 (513 epochs).
// Uniform 3-barrier epoch skeleton; all values deterministically initialized.
__device__ __forceinline__ void load_wfrag(const float* __restrict__ W, int j0, int w,
                                           int l15, int lhi, bf16x8_t wf[2][8]) {
  #pragma unroll
  for (int m = 0; m < 2; ++m) {
    const int idx = m * 16 + l15;           // row within the 24
    const int gg = idx >> 3, uu = idx & 7;
    #pragma unroll
    for (int c = 0; c < 8; ++c) {
      f32x4_t v0 = {0.f, 0.f, 0.f, 0.f}, v1 = {0.f, 0.f, 0.f, 0.f};
      if (idx < 24) {
        const float* p = W + (size_t)((gg << 10) + j0 + uu) * 1024
                           + (w << 8) + (c << 5) + (lhi << 3);
        v0 = *(const f32x4_t*)p;
        v1 = *(const f32x4_t*)(p + 4);
      }
      bf16x8_t f;
      f[0] = (__bf16)v0[0]; f[1] = (__bf16)v0[1]; f[2] = (__bf16)v0[2]; f[3] = (__bf16)v0[3];
      f[4] = (__bf16)v1[0]; f[5] = (__bf16)v1[1]; f[6] = (__bf16)v1[2]; f[7] = (__bf16)v1[3];
      wf[m][c] = f;
    }
  }
}

__global__ __launch_bounds__(256, 1) void gru_fused(
    const float* __restrict__ xg,       // [8,512,3072] layer-0 input gates (incl b_ih0)
    const float* __restrict__ w_hh,     // [2,3072,1024]
    const float* __restrict__ w_ih,     // [2,3072,1024]
    const float* __restrict__ b_hh,     // [2,3072]
    const float* __restrict__ b_ih,     // [2,3072]
    const float* __restrict__ h0f,      // [2,8,1024]
    unsigned short* __restrict__ y,     // [8,512,1024] final (layer-1) output bf16
    unsigned short* __restrict__ hb,    // [2 layers][2 slots][16*1024] bf16
    int* __restrict__ flags)            // [256*32]
{
  __shared__ __align__(16) float red[4 * 3 * 256];   // 12KB: [wave][slot][16x16 f32]
  const int tid = threadIdx.x;
  const int blk = blockIdx.x;
  const int layer = blk >> 7;
  const int j0 = (blk & 127) * 8;
  const int w = tid >> 6;
  const int l = tid & 63;
  const int l15 = l & 15;
  const int lhi = l >> 4;

  const float* whh = w_hh + (size_t)layer * G3H * H_;
  const float* bhh = b_hh + (size_t)layer * G3H;
  const float* bih = b_ih + (size_t)layer * G3H;

  bf16x8_t wfh[2][8], wfi[2][8];
  // deterministic init of wfi (layer 0 never loads it)
  #pragma unroll
  for (int m = 0; m < 2; ++m)
    #pragma unroll
    for (int c = 0; c < 8; ++c) wfi[m][c] = (bf16x8_t)(__bf16)0.0f;
  load_wfrag(whh, j0, w, l15, lhi, wfh);
  if (layer == 1) load_wfrag(w_ih + (size_t)G3H * H_, j0, w, l15, lhi, wfi);

  // per-gate-thread state (tid<64): u = tid&7, b = tid>>3
  const int u = tid & 7;
  const int b = tid >> 3;
  float g_br = 0.f, g_bz = 0.f, g_bnh = 0.f, g_bni = 0.f, hprev = 0.f;
  const float* xgp = nullptr;
  if (tid < 64) {
    float bhr = bhh[j0 + u], bhz = bhh[1024 + j0 + u], bhn = bhh[2048 + j0 + u];
    if (layer == 0) {
      g_br = bhr; g_bz = bhz; g_bnh = bhn;
      xgp = xg + (size_t)(b * S_) * G3H + j0 + u;
    } else {
      g_br = bhr + bih[j0 + u];
      g_bz = bhz + bih[1024 + j0 + u];
      g_bnh = bhn;
      g_bni = bih[2048 + j0 + u];
    }
    hprev = h0f[(size_t)layer * 8192 + b * 1024 + j0 + u];
  }

  unsigned short* const hb0 = hb;            // layer-0 slots
  unsigned short* const hb1 = hb + 32768;    // layer-1 slots
  const int frag_off = l15 * 1024 + (w << 8) + (lhi << 3);

  for (int e = 0; e <= S_; ++e) {
    const bool active = (layer == 0) ? (e < S_) : (e >= 1);
    const int t = (layer == 0) ? e : (e - 1);

    // deterministic init every epoch (no undef regs anywhere)
    f32x4_t hv[8], yv[8];
    #pragma unroll
    for (int c = 0; c < 8; ++c) { hv[c] = (f32x4_t)0.0f; yv[c] = (f32x4_t)0.0f; }
    float xr = 0.f, xz = 0.f, xn = 0.f;

    f32x4_t a0h = (f32x4_t)0.0f, a1h = (f32x4_t)0.0f, a1i = (f32x4_t)0.0f;

    if (active) {
      // ---- B-frag loads (L2-bypassing; served by Infinity Cache) ----
      if (layer == 0) {
        const unsigned short* hp0 = hb0 + (e & 1) * 16384 + frag_off;
        #pragma unroll
        for (int c = 0; c < 8; ++c)
          asm volatile("global_load_dwordx4 %0, %1, off offset:%2 sc0 sc1"
                       : "=v"(hv[c]) : "v"(hp0), "i"(c * 64) : "memory");
        if (tid < 64) {
          const float* p = xgp + (size_t)t * G3H;
          xr = p[0]; xz = p[1024]; xn = p[2048];
        }
      } else {
        const unsigned short* yp0 = hb0 + (e & 1) * 16384 + frag_off;        // y0_t
        const unsigned short* hp0 = hb1 + ((e + 1) & 1) * 16384 + frag_off;  // h1_{t-1}
        #pragma unroll
        for (int c = 0; c < 8; ++c)
          asm volatile("global_load_dwordx4 %0, %1, off offset:%2 sc0 sc1"
                       : "=v"(yv[c]) : "v"(yp0), "i"(c * 64) : "memory");
        #pragma unroll
        for (int c = 0; c < 8; ++c)
          asm volatile("global_load_dwordx4 %0, %1, off offset:%2 sc0 sc1"
                       : "=v"(hv[c]) : "v"(hp0), "i"(c * 64) : "memory");
      }
      asm volatile("s_waitcnt vmcnt(0)" ::: "memory");
      __builtin_amdgcn_sched_barrier(0);

      // ---- MFMA matvecs ----
      #pragma unroll
      for (int c = 0; c < 8; ++c) {
        bf16x8_t hfc = __builtin_bit_cast(bf16x8_t, hv[c]);
        a0h = __builtin_amdgcn_mfma_f32_16x16x32_bf16(wfh[0][c], hfc, a0h, 0, 0, 0);
        a1h = __builtin_amdgcn_mfma_f32_16x16x32_bf16(wfh[1][c], hfc, a1h, 0, 0, 0);
      }
      if (layer == 1) {
        #pragma unroll
        for (int c = 0; c < 8; ++c) {
          bf16x8_t yfc = __builtin_bit_cast(bf16x8_t, yv[c]);
          a0h = __builtin_amdgcn_mfma_f32_16x16x32_bf16(wfi[0][c], yfc, a0h, 0, 0, 0);
          a1i = __builtin_amdgcn_mfma_f32_16x16x32_bf16(wfi[1][c], yfc, a1i, 0, 0, 0);
        }
      }
      // ---- cross-wave K-reduction via LDS (all 3 slots, unconditional) ----
      *(f32x4_t*)&red[(w * 3 + 0) * 256 + (l << 2)] = a0h;
      *(f32x4_t*)&red[(w * 3 + 1) * 256 + (l << 2)] = a1h;
      *(f32x4_t*)&red[(w * 3 + 2) * 256 + (l << 2)] = a1i;
    }
    __syncthreads();   // (1) reduction barrier — uniform

    if (active && tid < 64) {
      const int base0 = (((u >> 2) << 4 | b) << 2) + (u & 3);   // tile row u
      const int base1 = base0 + 128;                            // tile row 8+u
      float aR = 0.f, aZ = 0.f, aNh = 0.f, aNi = 0.f;
      #pragma unroll
      for (int ww = 0; ww < 4; ++ww) {
        aR  += red[ww * 768 + base0];
        aZ  += red[ww * 768 + base1];
        aNh += red[ww * 768 + 256 + base0];
        aNi += red[ww * 768 + 512 + base0];
      }
      float r, z, n;
      if (layer == 0) {
        r = fast_sigmoid(xr + g_br + aR);
        z = fast_sigmoid(xz + g_bz + aZ);
        n = fast_tanh(xn + r * (aNh + g_bnh));
      } else {
        r = fast_sigmoid(aR + g_br);
        z = fast_sigmoid(aZ + g_bz);
        n = fast_tanh(aNi + g_bni + r * (aNh + g_bnh));
      }
      hprev = (1.0f - z) * n + z * hprev;
      unsigned short hv16 = f2bf(hprev);
      unsigned short* hdst = (layer == 0) ? (hb0 + ((e + 1) & 1) * 16384)
                                          : (hb1 + (e & 1) * 16384);
      if (layer == 1)
        y[(((size_t)(b * S_ + t)) << 10) + j0 + u] = hv16;   // normal store (GEMM reads)
      asm volatile("global_store_short %0, %1, off sc0 sc1"
                   :: "v"(hdst + b * 1024 + j0 + u), "v"(hv16) : "memory");
    }
    // ---- R3-exact release sequence (unconditional) ----
    asm volatile("s_waitcnt vmcnt(0)" ::: "memory");
    __syncthreads();   // (2) all stores of this block drained & joined
    if (tid == 0)
      __hip_atomic_store(&flags[blk * 32], e + 1,
                         __ATOMIC_RELAXED, __HIP_MEMORY_SCOPE_AGENT);
    while (__hip_atomic_load(&flags[tid * 32],
                             __ATOMIC_RELAXED, __HIP_MEMORY_SCOPE_AGENT) < e + 1)
      __builtin_amdgcn_s_sleep(1);
    __syncthreads();   // (3) epoch join
  }
}

// ---------------- launch ----------------
extern "C" void kernel_launch(void* const* d_in, const int* in_sizes, int n_in,
                              void* d_out, int out_size, void* d_ws, size_t ws_size,
                              hipStream_t stream) {
  (void)in_sizes; (void)n_in; (void)out_size; (void)ws_size;
  const float* concepts = (const float*)d_in[0];
  const int*   seq      = (const int*)d_in[1];
  const float* emb      = (const float*)d_in[2];
  const float* w_ih     = (const float*)d_in[3];
  const float* w_hh     = (const float*)d_in[4];
  const float* b_ih     = (const float*)d_in[5];
  const float* b_hh     = (const float*)d_in[6];
  const float* fc_w     = (const float*)d_in[7];
  const float* fc_b     = (const float*)d_in[8];
  const float* c2h_w    = (const float*)d_in[9];
  const float* c2h_b    = (const float*)d_in[10];
  float* out = (float*)d_out;

  char* ws = (char*)d_ws;
  size_t off = 0;
  auto alloc = [&](size_t bytes) {
    char* p = ws + off;
    off += (bytes + 255) & ~(size_t)255;
    return p;
  };
  unsigned short* xy   = (unsigned short*)alloc((size_t)B_ * S_ * H_ * 2);   // x bf16, then y
  float*          xg   = (float*)alloc((size_t)B_ * S_ * G3H * 4);           // layer-0 input gates
  unsigned short* wihb = (unsigned short*)alloc((size_t)G3H * H_ * 2);       // layer-0 W_ih bf16
  unsigned short* fcwb = (unsigned short*)alloc((size_t)V_ * H_ * 2);
  float*          ctx  = (float*)alloc((size_t)B_ * D_ * 4);
  float*          h0l  = (float*)alloc((size_t)2 * B_ * H_ * 4);
  unsigned short* hb   = (unsigned short*)alloc((size_t)2 * 2 * 16 * 1024 * 2);  // 128KB
  int*            flags= (int*)alloc((size_t)256 * 32 * 4);                      // 32KB (follows hb)

  // zero hb (both layers/slots incl. pad rows) + flags in one pass (contiguous)
  zero_buf<<<dim3(40), dim3(256), 0, stream>>>((uint4*)hb, (131072 + 32768) / 16);
  ctx_mean<<<dim3(8), dim3(256), 0, stream>>>(concepts, ctx);
  h0_compute<<<dim3(64), dim3(256), 0, stream>>>(ctx, c2h_w, c2h_b, h0l, hb);
  gather_embed<<<dim3(B_ * S_), dim3(256), 0, stream>>>(seq, emb, xy);
  f32_to_bf16<<<dim3(1024), dim3(256), 0, stream>>>(w_ih, wihb, (long)G3H * H_ / 4);
  f32_to_bf16<<<dim3(2048), dim3(256), 0, stream>>>(fc_w, fcwb, (long)V_ * H_ / 4);

  // layer-0 input gates (GEMM)
  gemm_bt_bf16<<<dim3(G3H / 128, (B_ * S_) / 128), dim3(256), 0, stream>>>(
      xy, wihb, xg, b_ih, B_ * S_, G3H, H_);

  // fused 2-layer skewed recurrence
  gru_fused<<<dim3(256), dim3(256), 0, stream>>>(
      xg, w_hh, w_ih, b_hh, b_ih, h0l, xy, hb, flags);

  // logits
  gemm_bt_bf16<<<dim3(V_ / 128, (B_ * S_) / 128), dim3(256), 0, stream>>>(
      xy, fcwb, out, fc_b, B_ * S_, V_, H_);
}